// Round 8
// baseline (3486.637 us; speedup 1.0000x reference)
//
#include <hip/hip_runtime.h>

#define B 8
#define F 257
#define C 8
#define T 800
#define TAPS 5
#define DELAY 3
#define K 40         // TAPS*C
#define NCOL 48      // K + C
#define T0 7         // DELAY + TAPS - 1
#define BF (B*F)     // 2056

typedef __bf16 bf16x8 __attribute__((ext_vector_type(8)));
typedef __bf16 bf16x4 __attribute__((ext_vector_type(4)));
typedef float f32x4 __attribute__((ext_vector_type(4)));

// ---------------- kernel 1: sqrt inverse power weights (0 for t<T0) ----------------
__global__ __launch_bounds__(256) void power_kernel(const float* __restrict__ sr,
                                                    const float* __restrict__ si,
                                                    float* __restrict__ W) {
    int bf = blockIdx.x;
    const float* srp = sr + (size_t)bf * C * T;
    const float* sip = si + (size_t)bf * C * T;
    int t0 = threadIdx.x * 4;
    if (t0 < T) {
        float s[4] = {0.f, 0.f, 0.f, 0.f};
#pragma unroll
        for (int c = 0; c < C; ++c) {
            float4 a = *(const float4*)(srp + c * T + t0);
            float4 b = *(const float4*)(sip + c * T + t0);
            s[0] = fmaf(a.x, a.x, fmaf(b.x, b.x, s[0]));
            s[1] = fmaf(a.y, a.y, fmaf(b.y, b.y, s[1]));
            s[2] = fmaf(a.z, a.z, fmaf(b.z, b.z, s[2]));
            s[3] = fmaf(a.w, a.w, fmaf(b.w, b.w, s[3]));
        }
        float4 w;
        float* wp = (float*)&w;
#pragma unroll
        for (int e = 0; e < 4; ++e) {
            float v = fmaxf(s[e] * (1.0f / C), 1e-7f);
            wp[e] = (t0 + e < T0) ? 0.f : rsqrtf(v);   // sqrt(1/power)
        }
        *(float4*)(W + (size_t)bf * T + t0) = w;
    }
}

// ---------------- kernel 2: R,P via bf16 MFMA, sqrt(w)-symmetrized Gram ----------------
#define WB 10624

__global__ __launch_bounds__(256, 3) void rp_mfma_kernel(const float* __restrict__ mr,
                                                         const float* __restrict__ mi,
                                                         const float* __restrict__ W,
                                                         float2* __restrict__ Rout,
                                                         float2* __restrict__ Pout) {
    __shared__ __align__(16) unsigned char SH[4 * WB];
    const int lane = threadIdx.x & 63;
    const int wid = threadIdx.x >> 6;
    const int bf = blockIdx.x * 4 + wid;
    unsigned char* base = SH + wid * WB;
    float* sre = (float*)(base + 7680);
    float* sim_ = (float*)(base + 9088);
    float* wsh = (float*)(base + 10496);

    const float* mrp = mr + (size_t)bf * C * T;
    const float* mip = mi + (size_t)bf * C * T;
    const float* Wp  = W  + (size_t)bf * T;

    const int q = lane >> 4, col = lane & 15;
    const int pc = lane >> 3, pg = lane & 7;     // phase-B task: channel, 4t-group

    const int PM[6] = {0, 0, 0, 1, 1, 2};
    const int PN[6] = {0, 1, 2, 1, 2, 2};

    f32x4 accRe[6], accIr[6], accRi[6];
#pragma unroll
    for (int p = 0; p < 6; ++p) {
        accRe[p] = (f32x4){0.f, 0.f, 0.f, 0.f};
        accIr[p] = (f32x4){0.f, 0.f, 0.f, 0.f};
        accRi[p] = (f32x4){0.f, 0.f, 0.f, 0.f};
    }

    for (int ks = 0; ks < 25; ++ks) {
        const int tb = ks * 32;

        // ---- Phase A: vectorized global -> fp32 LDS scratch ----
#pragma unroll
        for (int it = 0; it < 3; ++it) {
            int task = lane + it * 64;
            if (task < 160) {
                int pl = task / 80;
                int rem = task - pl * 80;
                int c = rem / 10, grp = rem - c * 10;
                int tg = tb - 8 + grp * 4;
                const float* srcp = pl ? mip : mrp;
                float4 v = make_float4(0.f, 0.f, 0.f, 0.f);
                if (tg >= 0) v = *(const float4*)(srcp + c * T + tg);
                *(float4*)((pl ? sim_ : sre) + c * 44 + grp * 4) = v;
            } else if (task < 168) {
                int grp = task - 160;
                *(float4*)(wsh + grp * 4) = *(const float4*)(Wp + tb + grp * 4);
            }
        }

        // ---- Phase B: build 6 shift-variant bf16 rows from scratch ----
        {
            float yre[12], yim[12];
            int ybase = pc * 44 + pg * 4;
#pragma unroll
            for (int i = 1; i <= 11; ++i) {
                yre[i] = sre[ybase + i];
                yim[i] = sim_[ybase + i];
            }
            float4 w4 = *(const float4*)(wsh + pg * 4);
            float wv[4] = {w4.x, w4.y, w4.z, w4.w};
#pragma unroll
            for (int v = 0; v < 6; ++v) {
                int row = (v < 5) ? (v * 8 + pc) : (40 + pc);
                int off = (v < 5) ? (5 - v) : 8;
                bf16x4 zr, zi;
#pragma unroll
                for (int e = 0; e < 4; ++e) {
                    zr[e] = (__bf16)(wv[e] * yre[off + e]);
                    zi[e] = (__bf16)(wv[e] * yim[off + e]);
                }
                *(bf16x4*)(base + row * 80 + pg * 8) = zr;
                *(bf16x4*)(base + 3840 + row * 80 + pg * 8) = zi;
            }
        }

        // ---- fragments (shared A/B operand) + 24 MFMA ----
        bf16x8 fr[3], fi[3];
#pragma unroll
        for (int X = 0; X < 3; ++X) {
            fr[X] = *(const bf16x8*)(base + (X * 16 + col) * 80 + q * 16);
            fi[X] = *(const bf16x8*)(base + 3840 + (X * 16 + col) * 80 + q * 16);
        }
#pragma unroll
        for (int p = 0; p < 6; ++p) {
            int mt = PM[p], nt = PN[p];
            accRe[p] = __builtin_amdgcn_mfma_f32_16x16x32_bf16(fr[mt], fr[nt], accRe[p], 0, 0, 0);
            accRe[p] = __builtin_amdgcn_mfma_f32_16x16x32_bf16(fi[mt], fi[nt], accRe[p], 0, 0, 0);
            accIr[p] = __builtin_amdgcn_mfma_f32_16x16x32_bf16(fi[mt], fr[nt], accIr[p], 0, 0, 0);
            accRi[p] = __builtin_amdgcn_mfma_f32_16x16x32_bf16(fr[mt], fi[nt], accRi[p], 0, 0, 0);
        }
    }

    // ---- epilogue: D row=(lane>>4)*4+reg, col=lane&15 (m89); Hermitian mirror ----
    float2* Rp = Rout + (size_t)bf * K * K;
    float2* Pp = Pout + (size_t)bf * K * C;
#pragma unroll
    for (int p = 0; p < 6; ++p) {
        int mt = PM[p], nt = PN[p];
#pragma unroll
        for (int r = 0; r < 4; ++r) {
            int m = mt * 16 + q * 4 + r;
            int n = nt * 16 + col;
            float re = accRe[p][r];
            float im = accIr[p][r] - accRi[p][r];
            if (m < K) {
                if (n < K) Rp[m * K + n] = make_float2(re, im);
                else       Pp[m * C + (n - K)] = make_float2(re, im);
            }
            if (mt != nt && m < K && n < K)
                Rp[n * K + m] = make_float2(re, -im);
        }
    }
}

// ---------------- kernel 3: solve R G = P (complex LU, partial pivot) ----------------
__global__ __launch_bounds__(64) void solve_kernel(const float2* __restrict__ Rin,
                                                   const float2* __restrict__ Pin,
                                                   float2* __restrict__ Gout) {
    __shared__ float2 aug[K][NCOL + 1];
    int bf = blockIdx.x;
    int lane = threadIdx.x;

    for (int i = lane; i < K * K; i += 64) {
        int r = i / K, c2 = i % K;
        float2 v = Rin[(size_t)bf * K * K + i];
        if (r == c2) v.x += 1e-10f;
        aug[r][c2] = v;
    }
    for (int i = lane; i < K * C; i += 64)
        aug[i >> 3][K + (i & 7)] = Pin[(size_t)bf * K * C + i];
    __syncthreads();

    for (int j = 0; j < K; ++j) {
        float mag = -1.0f;
        int idx = lane;
        if (lane < K && lane >= j) {
            float2 v = aug[lane][j];
            mag = fabsf(v.x) + fabsf(v.y);
        }
        for (int off = 32; off; off >>= 1) {
            float om = __shfl_xor(mag, off);
            int oi = __shfl_xor(idx, off);
            if (om > mag || (om == mag && oi < idx)) { mag = om; idx = oi; }
        }
        int piv = idx;
        if (piv != j && lane < NCOL) {
            float2 tmp = aug[j][lane];
            aug[j][lane] = aug[piv][lane];
            aug[piv][lane] = tmp;
        }
        __syncthreads();
        float2 d = aug[j][j];
        float den = d.x * d.x + d.y * d.y;
        float2 invp = make_float2(d.x / den, -d.y / den);
        if (lane > j && lane < K) {
            float2 v = aug[lane][j];
            float2 l = make_float2(v.x * invp.x - v.y * invp.y,
                                   v.x * invp.y + v.y * invp.x);
            for (int n = j + 1; n < NCOL; ++n) {
                float2 u = aug[j][n];
                float2 a = aug[lane][n];
                a.x -= l.x * u.x - l.y * u.y;
                a.y -= l.x * u.y + l.y * u.x;
                aug[lane][n] = a;
            }
            aug[lane][j] = l;
        }
        __syncthreads();
    }

    for (int j = K - 1; j >= 0; --j) {
        float2 d = aug[j][j];
        float den = d.x * d.x + d.y * d.y;
        float2 invp = make_float2(d.x / den, -d.y / den);
        if (lane < C) {
            float2 v = aug[j][K + lane];
            aug[j][K + lane] = make_float2(v.x * invp.x - v.y * invp.y,
                                           v.x * invp.y + v.y * invp.x);
        }
        __syncthreads();
        for (int id = lane; id < j * C; id += 64) {
            int i = id >> 3, e = id & 7;
            float2 u = aug[i][j];
            float2 x = aug[j][K + e];
            float2 a = aug[i][K + e];
            a.x -= u.x * x.x - u.y * x.y;
            a.y -= u.x * x.y + u.y * x.x;
            aug[i][K + e] = a;
        }
        __syncthreads();
    }

    for (int i = lane; i < K * C; i += 64)
        Gout[(size_t)bf * K * C + i] = aug[i >> 3][K + (i & 7)];
}

// ---------------- kernel 4: X = Y - G^H Yt, time-chunked, R6 register pattern ----------------
#define TCX 200
#define HALOX 7
#define LX (TCX + HALOX)   // 207

__global__ __launch_bounds__(256, 4) void x_kernel(const float* __restrict__ mr,
                                                   const float* __restrict__ mi,
                                                   const float2* __restrict__ Gin,
                                                   const int* __restrict__ ilens,
                                                   float2* __restrict__ out) {
    __shared__ float2 Ysh[C][LX];     // 13248 B
    __shared__ float2 Gsh[K][C];      // 2560 B
    int gid = blockIdx.x;
    int bf = gid >> 2;
    int chn = gid & 3;
    int ts = chn * TCX;
    int b = bf / F;
    int tid = threadIdx.x;
    const float* mrp = mr + (size_t)bf * C * T;
    const float* mip = mi + (size_t)bf * C * T;

    for (int i = tid; i < C * LX; i += 256) {
        int c = i / LX, l = i - c * LX;
        int tau = ts - HALOX + l;
        Ysh[c][l] = (tau >= 0) ? make_float2(mrp[c * T + tau], mip[c * T + tau])
                               : make_float2(0.f, 0.f);
    }
    for (int i = tid; i < K * C; i += 256)
        Gsh[i >> 3][i & 7] = Gin[(size_t)bf * K * C + i];
    __syncthreads();

    if (tid < TCX) {
        int t = ts + tid;
        int l = tid + HALOX;
        int len = ilens[b];
        float2 acc[C];
#pragma unroll
        for (int e = 0; e < C; ++e) acc[e] = Ysh[e][l];

#pragma unroll
        for (int k = 0; k < TAPS; ++k) {
            __builtin_amdgcn_sched_barrier(0);   // fence hoisting window -> bounded live set
#pragma unroll
            for (int c = 0; c < C; ++c) {
                int a = k * C + c;
                float2 g[C];
#pragma unroll
                for (int e = 0; e < C; ++e) g[e] = Gsh[a][e];
                float2 yt = Ysh[c][l - DELAY - k];
#pragma unroll
                for (int e = 0; e < C; ++e) {
                    // acc -= conj(g) * yt
                    acc[e].x = fmaf(-g[e].x, yt.x, acc[e].x);
                    acc[e].x = fmaf(-g[e].y, yt.y, acc[e].x);
                    acc[e].y = fmaf(-g[e].x, yt.y, acc[e].y);
                    acc[e].y = fmaf(g[e].y, yt.x, acc[e].y);
                }
            }
        }

        bool ok = (t < len);
#pragma unroll
        for (int e = 0; e < C; ++e) {
            float2 v = ok ? acc[e] : make_float2(0.f, 0.f);
            out[((size_t)bf * C + e) * T + t] = v;
        }
    }
}

extern "C" void kernel_launch(void* const* d_in, const int* in_sizes, int n_in,
                              void* d_out, int out_size, void* d_ws, size_t ws_size,
                              hipStream_t stream) {
    const float* sep_r = (const float*)d_in[0];
    const float* sep_i = (const float*)d_in[1];
    const float* mix_r = (const float*)d_in[2];
    const float* mix_i = (const float*)d_in[3];
    const int* ilens   = (const int*)d_in[4];

    float* ws = (float*)d_ws;
    float* W = ws;                                        // BF*T floats
    float2* Rws = (float2*)(ws + (size_t)BF * T);         // BF*K*K float2
    float2* Gws = Rws + (size_t)BF * K * K;               // BF*K*C float2 (P then G in-place)

    power_kernel<<<BF, 256, 0, stream>>>(sep_r, sep_i, W);
    rp_mfma_kernel<<<BF / 4, 256, 0, stream>>>(mix_r, mix_i, W, Rws, Gws);
    solve_kernel<<<BF, 64, 0, stream>>>(Rws, Gws, Gws);
    x_kernel<<<BF * 4, 256, 0, stream>>>(mix_r, mix_i, Gws, ilens, (float2*)d_out);
}

// Round 9
// 313.238 us; speedup vs baseline: 11.1309x; 11.1309x over previous
//
#include <hip/hip_runtime.h>

#define B 8
#define F 257
#define C 8
#define T 800
#define TAPS 5
#define DELAY 3
#define K 40         // TAPS*C
#define NCOL 48      // K + C
#define T0 7         // DELAY + TAPS - 1
#define BF (B*F)     // 2056

typedef __bf16 bf16x8 __attribute__((ext_vector_type(8)));
typedef __bf16 bf16x4 __attribute__((ext_vector_type(4)));
typedef float f32x4 __attribute__((ext_vector_type(4)));

// ---------------- kernel 1: sqrt inverse power weights (0 for t<T0) ----------------
__global__ __launch_bounds__(256) void power_kernel(const float* __restrict__ sr,
                                                    const float* __restrict__ si,
                                                    float* __restrict__ W) {
    int bf = blockIdx.x;
    const float* srp = sr + (size_t)bf * C * T;
    const float* sip = si + (size_t)bf * C * T;
    int t0 = threadIdx.x * 4;
    if (t0 < T) {
        float s[4] = {0.f, 0.f, 0.f, 0.f};
#pragma unroll
        for (int c = 0; c < C; ++c) {
            float4 a = *(const float4*)(srp + c * T + t0);
            float4 b = *(const float4*)(sip + c * T + t0);
            s[0] = fmaf(a.x, a.x, fmaf(b.x, b.x, s[0]));
            s[1] = fmaf(a.y, a.y, fmaf(b.y, b.y, s[1]));
            s[2] = fmaf(a.z, a.z, fmaf(b.z, b.z, s[2]));
            s[3] = fmaf(a.w, a.w, fmaf(b.w, b.w, s[3]));
        }
        float4 w;
        float* wp = (float*)&w;
#pragma unroll
        for (int e = 0; e < 4; ++e) {
            float v = fmaxf(s[e] * (1.0f / C), 1e-7f);
            wp[e] = (t0 + e < T0) ? 0.f : rsqrtf(v);   // sqrt(1/power)
        }
        *(float4*)(W + (size_t)bf * T + t0) = w;
    }
}

// ---------------- kernel 2: R,P via bf16 MFMA, sqrt(w)-symmetrized Gram ----------------
#define WB 10624

__global__ __launch_bounds__(256, 3) void rp_mfma_kernel(const float* __restrict__ mr,
                                                         const float* __restrict__ mi,
                                                         const float* __restrict__ W,
                                                         float2* __restrict__ Rout,
                                                         float2* __restrict__ Pout) {
    __shared__ __align__(16) unsigned char SH[4 * WB];
    const int lane = threadIdx.x & 63;
    const int wid = threadIdx.x >> 6;
    const int bf = blockIdx.x * 4 + wid;
    unsigned char* base = SH + wid * WB;
    float* sre = (float*)(base + 7680);
    float* sim_ = (float*)(base + 9088);
    float* wsh = (float*)(base + 10496);

    const float* mrp = mr + (size_t)bf * C * T;
    const float* mip = mi + (size_t)bf * C * T;
    const float* Wp  = W  + (size_t)bf * T;

    const int q = lane >> 4, col = lane & 15;
    const int pc = lane >> 3, pg = lane & 7;     // phase-B task: channel, 4t-group

    const int PM[6] = {0, 0, 0, 1, 1, 2};
    const int PN[6] = {0, 1, 2, 1, 2, 2};

    f32x4 accRe[6], accIr[6], accRi[6];
#pragma unroll
    for (int p = 0; p < 6; ++p) {
        accRe[p] = (f32x4){0.f, 0.f, 0.f, 0.f};
        accIr[p] = (f32x4){0.f, 0.f, 0.f, 0.f};
        accRi[p] = (f32x4){0.f, 0.f, 0.f, 0.f};
    }

    for (int ks = 0; ks < 25; ++ks) {
        const int tb = ks * 32;

        // ---- Phase A: vectorized global -> fp32 LDS scratch ----
#pragma unroll
        for (int it = 0; it < 3; ++it) {
            int task = lane + it * 64;
            if (task < 160) {
                int pl = task / 80;
                int rem = task - pl * 80;
                int c = rem / 10, grp = rem - c * 10;
                int tg = tb - 8 + grp * 4;
                const float* srcp = pl ? mip : mrp;
                float4 v = make_float4(0.f, 0.f, 0.f, 0.f);
                if (tg >= 0) v = *(const float4*)(srcp + c * T + tg);
                *(float4*)((pl ? sim_ : sre) + c * 44 + grp * 4) = v;
            } else if (task < 168) {
                int grp = task - 160;
                *(float4*)(wsh + grp * 4) = *(const float4*)(Wp + tb + grp * 4);
            }
        }

        // ---- Phase B: build 6 shift-variant bf16 rows from scratch ----
        {
            float yre[12], yim[12];
            int ybase = pc * 44 + pg * 4;
#pragma unroll
            for (int i = 1; i <= 11; ++i) {
                yre[i] = sre[ybase + i];
                yim[i] = sim_[ybase + i];
            }
            float4 w4 = *(const float4*)(wsh + pg * 4);
            float wv[4] = {w4.x, w4.y, w4.z, w4.w};
#pragma unroll
            for (int v = 0; v < 6; ++v) {
                int row = (v < 5) ? (v * 8 + pc) : (40 + pc);
                int off = (v < 5) ? (5 - v) : 8;
                bf16x4 zr, zi;
#pragma unroll
                for (int e = 0; e < 4; ++e) {
                    zr[e] = (__bf16)(wv[e] * yre[off + e]);
                    zi[e] = (__bf16)(wv[e] * yim[off + e]);
                }
                *(bf16x4*)(base + row * 80 + pg * 8) = zr;
                *(bf16x4*)(base + 3840 + row * 80 + pg * 8) = zi;
            }
        }

        // ---- fragments (shared A/B operand) + 24 MFMA ----
        bf16x8 fr[3], fi[3];
#pragma unroll
        for (int X = 0; X < 3; ++X) {
            fr[X] = *(const bf16x8*)(base + (X * 16 + col) * 80 + q * 16);
            fi[X] = *(const bf16x8*)(base + 3840 + (X * 16 + col) * 80 + q * 16);
        }
#pragma unroll
        for (int p = 0; p < 6; ++p) {
            int mt = PM[p], nt = PN[p];
            accRe[p] = __builtin_amdgcn_mfma_f32_16x16x32_bf16(fr[mt], fr[nt], accRe[p], 0, 0, 0);
            accRe[p] = __builtin_amdgcn_mfma_f32_16x16x32_bf16(fi[mt], fi[nt], accRe[p], 0, 0, 0);
            accIr[p] = __builtin_amdgcn_mfma_f32_16x16x32_bf16(fi[mt], fr[nt], accIr[p], 0, 0, 0);
            accRi[p] = __builtin_amdgcn_mfma_f32_16x16x32_bf16(fr[mt], fi[nt], accRi[p], 0, 0, 0);
        }
    }

    // ---- epilogue: D row=(lane>>4)*4+reg, col=lane&15 (m89); Hermitian mirror ----
    float2* Rp = Rout + (size_t)bf * K * K;
    float2* Pp = Pout + (size_t)bf * K * C;
#pragma unroll
    for (int p = 0; p < 6; ++p) {
        int mt = PM[p], nt = PN[p];
#pragma unroll
        for (int r = 0; r < 4; ++r) {
            int m = mt * 16 + q * 4 + r;
            int n = nt * 16 + col;
            float re = accRe[p][r];
            float im = accIr[p][r] - accRi[p][r];
            if (m < K) {
                if (n < K) Rp[m * K + n] = make_float2(re, im);
                else       Pp[m * C + (n - K)] = make_float2(re, im);
            }
            if (mt != nt && m < K && n < K)
                Rp[n * K + m] = make_float2(re, -im);
        }
    }
}

// ---------------- kernel 3: solve R G = P (complex LU, partial pivot) ----------------
__global__ __launch_bounds__(64) void solve_kernel(const float2* __restrict__ Rin,
                                                   const float2* __restrict__ Pin,
                                                   float2* __restrict__ Gout) {
    __shared__ float2 aug[K][NCOL + 1];
    int bf = blockIdx.x;
    int lane = threadIdx.x;

    for (int i = lane; i < K * K; i += 64) {
        int r = i / K, c2 = i % K;
        float2 v = Rin[(size_t)bf * K * K + i];
        if (r == c2) v.x += 1e-10f;
        aug[r][c2] = v;
    }
    for (int i = lane; i < K * C; i += 64)
        aug[i >> 3][K + (i & 7)] = Pin[(size_t)bf * K * C + i];
    __syncthreads();

    for (int j = 0; j < K; ++j) {
        float mag = -1.0f;
        int idx = lane;
        if (lane < K && lane >= j) {
            float2 v = aug[lane][j];
            mag = fabsf(v.x) + fabsf(v.y);
        }
        for (int off = 32; off; off >>= 1) {
            float om = __shfl_xor(mag, off);
            int oi = __shfl_xor(idx, off);
            if (om > mag || (om == mag && oi < idx)) { mag = om; idx = oi; }
        }
        int piv = idx;
        if (piv != j && lane < NCOL) {
            float2 tmp = aug[j][lane];
            aug[j][lane] = aug[piv][lane];
            aug[piv][lane] = tmp;
        }
        __syncthreads();
        float2 d = aug[j][j];
        float den = d.x * d.x + d.y * d.y;
        float2 invp = make_float2(d.x / den, -d.y / den);
        if (lane > j && lane < K) {
            float2 v = aug[lane][j];
            float2 l = make_float2(v.x * invp.x - v.y * invp.y,
                                   v.x * invp.y + v.y * invp.x);
            for (int n = j + 1; n < NCOL; ++n) {
                float2 u = aug[j][n];
                float2 a = aug[lane][n];
                a.x -= l.x * u.x - l.y * u.y;
                a.y -= l.x * u.y + l.y * u.x;
                aug[lane][n] = a;
            }
            aug[lane][j] = l;
        }
        __syncthreads();
    }

    for (int j = K - 1; j >= 0; --j) {
        float2 d = aug[j][j];
        float den = d.x * d.x + d.y * d.y;
        float2 invp = make_float2(d.x / den, -d.y / den);
        if (lane < C) {
            float2 v = aug[j][K + lane];
            aug[j][K + lane] = make_float2(v.x * invp.x - v.y * invp.y,
                                           v.x * invp.y + v.y * invp.x);
        }
        __syncthreads();
        for (int id = lane; id < j * C; id += 64) {
            int i = id >> 3, e = id & 7;
            float2 u = aug[i][j];
            float2 x = aug[j][K + e];
            float2 a = aug[i][K + e];
            a.x -= u.x * x.x - u.y * x.y;
            a.y -= u.x * x.y + u.y * x.x;
            aug[i][K + e] = a;
        }
        __syncthreads();
    }

    for (int i = lane; i < K * C; i += 64)
        Gout[(size_t)bf * K * C + i] = aug[i >> 3][K + (i & 7)];
}

// ---------------- kernel 4: X = Y - G^H Yt — R6 body, 2 chunks of 400 t ----------------
#define TCX 400
#define HALOX 7
#define LX (TCX + HALOX)   // 407

__global__ __launch_bounds__(256) void x_kernel(const float* __restrict__ mr,
                                                const float* __restrict__ mi,
                                                const float2* __restrict__ Gin,
                                                const int* __restrict__ ilens,
                                                float2* __restrict__ out) {
    __shared__ float2 Ysh[C][LX];     // 26048 B
    __shared__ float2 Gsh[K][C];      // 2560 B
    int gid = blockIdx.x;
    int bf = gid >> 1;
    int half = gid & 1;
    int ts = half * TCX;
    int b = bf / F;
    int tid = threadIdx.x;
    const float* mrp = mr + (size_t)bf * C * T;
    const float* mip = mi + (size_t)bf * C * T;

    for (int i = tid; i < C * LX; i += 256) {
        int c = i / LX, l = i - c * LX;
        int tau = ts - HALOX + l;
        Ysh[c][l] = (tau >= 0) ? make_float2(mrp[c * T + tau], mip[c * T + tau])
                               : make_float2(0.f, 0.f);
    }
    for (int i = tid; i < K * C; i += 256)
        Gsh[i >> 3][i & 7] = Gin[(size_t)bf * K * C + i];
    __syncthreads();

    int len = ilens[b];

    float2 acc[2][C];
#pragma unroll
    for (int it = 0; it < 2; ++it) {
        int tt = tid + it * 256;
#pragma unroll
        for (int e = 0; e < C; ++e)
            acc[it][e] = (tt < TCX) ? Ysh[e][tt + HALOX] : make_float2(0.f, 0.f);
    }

#pragma unroll
    for (int k = 0; k < TAPS; ++k) {
#pragma unroll
        for (int c = 0; c < C; ++c) {
            int a = k * C + c;
            float2 g[C];
#pragma unroll
            for (int e = 0; e < C; ++e) g[e] = Gsh[a][e];
#pragma unroll
            for (int it = 0; it < 2; ++it) {
                int tt = tid + it * 256;
                if (tt < TCX) {
                    float2 yt = Ysh[c][tt + HALOX - DELAY - k];
#pragma unroll
                    for (int e = 0; e < C; ++e) {
                        // acc -= conj(g) * yt
                        acc[it][e].x = fmaf(-g[e].x, yt.x, acc[it][e].x);
                        acc[it][e].x = fmaf(-g[e].y, yt.y, acc[it][e].x);
                        acc[it][e].y = fmaf(-g[e].x, yt.y, acc[it][e].y);
                        acc[it][e].y = fmaf(g[e].y, yt.x, acc[it][e].y);
                    }
                }
            }
        }
    }

#pragma unroll
    for (int it = 0; it < 2; ++it) {
        int tt = tid + it * 256;
        if (tt < TCX) {
            int t = ts + tt;
            bool ok = (t < len);
#pragma unroll
            for (int e = 0; e < C; ++e) {
                float2 v = ok ? acc[it][e] : make_float2(0.f, 0.f);
                out[((size_t)bf * C + e) * T + t] = v;
            }
        }
    }
}

extern "C" void kernel_launch(void* const* d_in, const int* in_sizes, int n_in,
                              void* d_out, int out_size, void* d_ws, size_t ws_size,
                              hipStream_t stream) {
    const float* sep_r = (const float*)d_in[0];
    const float* sep_i = (const float*)d_in[1];
    const float* mix_r = (const float*)d_in[2];
    const float* mix_i = (const float*)d_in[3];
    const int* ilens   = (const int*)d_in[4];

    float* ws = (float*)d_ws;
    float* W = ws;                                        // BF*T floats
    float2* Rws = (float2*)(ws + (size_t)BF * T);         // BF*K*K float2
    float2* Gws = Rws + (size_t)BF * K * K;               // BF*K*C float2 (P then G in-place)

    power_kernel<<<BF, 256, 0, stream>>>(sep_r, sep_i, W);
    rp_mfma_kernel<<<BF / 4, 256, 0, stream>>>(mix_r, mix_i, W, Rws, Gws);
    solve_kernel<<<BF, 64, 0, stream>>>(Rws, Gws, Gws);
    x_kernel<<<BF * 2, 256, 0, stream>>>(mix_r, mix_i, Gws, ilens, (float2*)d_out);
}